// Round 1
// baseline (2592.330 us; speedup 1.0000x reference)
//
#include <hip/hip_runtime.h>

// Problem constants
#define HWP   4096      // H*W
#define CDIM  256
#define KCODES 8192
#define NROWS 32768     // B*H*W
#define BM 128
#define BN 128
#define BK 64
#define APAD 4
#define BPAD 4

// ---------------- Kernel 1: per-row L2 norms of x over C ----------------
__global__ __launch_bounds__(256) void norms_kernel(const float* __restrict__ x,
                                                    float* __restrict__ norms) {
    int bh = blockIdx.x;             // b*64 + h, 512 blocks
    int b = bh >> 6, h = bh & 63;
    int t = threadIdx.x;
    int w = t & 63, cg = t >> 6;     // cg in 0..3
    const float* base = x + (size_t)b * CDIM * HWP + h * 64 + w;
    float s = 0.f;
    #pragma unroll 4
    for (int c = cg * 64; c < cg * 64 + 64; ++c) {
        float v = base[(size_t)c * HWP];
        s = fmaf(v, v, s);
    }
    __shared__ float part[4][64];
    part[cg][w] = s;
    __syncthreads();
    if (t < 64) {
        float tot = part[0][t] + part[1][t] + part[2][t] + part[3][t];
        norms[bh * 64 + t] = sqrtf(tot);
    }
}

// ---------------- Kernel 2: fp32 GEMM (raw x · codebook^T) + tile argmax ----------------
// Grid: (64 k-blocks, 256 m-blocks), 256 threads. Writes per-(row, kblock) best val/idx.
__global__ __launch_bounds__(256, 2) void gemm_argmax_kernel(const float* __restrict__ x,
                                                             const float* __restrict__ cb,
                                                             float* __restrict__ pval,
                                                             int* __restrict__ pidx) {
    __shared__ float As[BK][BM + APAD];   // [cc][pp]
    __shared__ float Bs[BK][BN + BPAD];   // [cc][kk]

    int t  = threadIdx.x;
    int kb = blockIdx.x;                  // 0..63
    int mb = blockIdx.y;                  // 0..255
    int n0 = mb * BM;
    int b  = n0 >> 12;                    // n0 / 4096 (BM divides 4096)
    int p0 = n0 & 4095;
    int k0 = kb * BN;
    int ty = t >> 4, tx = t & 15;

    float acc[8][8];
    #pragma unroll
    for (int j = 0; j < 8; ++j)
        #pragma unroll
        for (int s = 0; s < 8; ++s) acc[j][s] = 0.f;

    const float* xbase = x + (size_t)b * CDIM * HWP + p0;

    for (int cs = 0; cs < CDIM; cs += BK) {
        __syncthreads();
        // Stage A tile: 64 cc x 128 pp. Lanes sweep pp -> coalesced global,
        // conflict-free LDS store (consecutive addresses).
        #pragma unroll
        for (int it = 0; it < (BM * BK) / 256; ++it) {
            int i  = t + it * 256;
            int pp = i & (BM - 1);
            int cc = i >> 7;
            As[cc][pp] = xbase[(size_t)(cs + cc) * HWP + pp];
        }
        // Stage B tile: 64 cc x 128 kk. Lanes sweep cc -> coalesced global.
        #pragma unroll
        for (int it = 0; it < (BN * BK) / 256; ++it) {
            int i  = t + it * 256;
            int cc = i & (BK - 1);
            int kk = i >> 6;
            Bs[cc][kk] = cb[(size_t)(k0 + kk) * CDIM + cs + cc];
        }
        __syncthreads();

        #pragma unroll 4
        for (int cc = 0; cc < BK; ++cc) {
            float4 a0 = *(const float4*)&As[cc][ty * 8];
            float4 a1 = *(const float4*)&As[cc][ty * 8 + 4];
            float4 b0 = *(const float4*)&Bs[cc][tx * 8];
            float4 b1 = *(const float4*)&Bs[cc][tx * 8 + 4];
            float av[8] = {a0.x, a0.y, a0.z, a0.w, a1.x, a1.y, a1.z, a1.w};
            float bv[8] = {b0.x, b0.y, b0.z, b0.w, b1.x, b1.y, b1.z, b1.w};
            #pragma unroll
            for (int j = 0; j < 8; ++j)
                #pragma unroll
                for (int s = 0; s < 8; ++s)
                    acc[j][s] = fmaf(av[j], bv[s], acc[j][s]);
        }
    }

    // Epilogue: per-thread argmax over its 8 codes (ascending s keeps lowest idx),
    // then cross-tx reduction per row (ascending tx keeps lowest idx).
    __syncthreads();
    float* rv = &As[0][0];                 // 128*16 floats
    int*   ri = (int*)&Bs[0][0];           // 128*16 ints
    #pragma unroll
    for (int j = 0; j < 8; ++j) {
        float bvv = acc[j][0];
        int   bss = 0;
        #pragma unroll
        for (int s = 1; s < 8; ++s)
            if (acc[j][s] > bvv) { bvv = acc[j][s]; bss = s; }
        int py = ty * 8 + j;
        rv[py * 16 + tx] = bvv;
        ri[py * 16 + tx] = k0 + tx * 8 + bss;
    }
    __syncthreads();
    if (t < 128) {
        float bvv = rv[t * 16];
        int   bii = ri[t * 16];
        #pragma unroll
        for (int q = 1; q < 16; ++q) {
            float v = rv[t * 16 + q];
            if (v > bvv) { bvv = v; bii = ri[t * 16 + q]; }
        }
        pval[(size_t)kb * NROWS + n0 + t] = bvv;
        pidx[(size_t)kb * NROWS + n0 + t] = bii;
    }
}

// ---------------- Kernel 3: final argmax across 64 k-blocks + loss partial ----------------
__global__ __launch_bounds__(256) void reduce_kernel(const float* __restrict__ pval,
                                                     const int* __restrict__ pidx,
                                                     const float* __restrict__ norms,
                                                     int* __restrict__ idx_best,
                                                     float* __restrict__ loss_sum) {
    int n = blockIdx.x * 256 + threadIdx.x;   // 128 blocks
    float bv = pval[n];
    int   bi = pidx[n];
    for (int kb = 1; kb < 64; ++kb) {
        float v = pval[(size_t)kb * NROWS + n];
        int   i = pidx[(size_t)kb * NROWS + n];
        if (v > bv) { bv = v; bi = i; }       // ascending kb -> first-index ties
    }
    idx_best[n] = bi;
    float nr  = fmaxf(norms[n], 1e-12f);
    float dot = bv / nr;                       // = z . q for this row

    __shared__ float red[256];
    red[threadIdx.x] = dot;
    __syncthreads();
    for (int off = 128; off > 0; off >>= 1) {
        if (threadIdx.x < off) red[threadIdx.x] += red[threadIdx.x + off];
        __syncthreads();
    }
    if (threadIdx.x == 0) atomicAdd(loss_sum, red[0]);
}

// ---------------- Kernel 4: gather q (raw codebook rows) + transpose write + losses ----------------
__global__ __launch_bounds__(256) void writeq_kernel(const float* __restrict__ cb,
                                                     const int* __restrict__ idx_best,
                                                     const float* __restrict__ loss_sum,
                                                     float* __restrict__ out) {
    int bh = blockIdx.x;            // 512 blocks (b*64 + h)
    int b = bh >> 6, h = bh & 63;
    int t = threadIdx.x;
    int w = t & 63, cg = t >> 6;
    int n = bh * 64 + w;
    int id = idx_best[n];
    const float* crow = cb + (size_t)id * CDIM;
    float* obase = out + (size_t)b * CDIM * HWP + h * 64 + w;
    #pragma unroll 4
    for (int c = cg * 64; c < cg * 64 + 64; ++c) {
        obase[(size_t)c * HWP] = crow[c];     // coalesced 64-lane writes
    }
    if (bh == 0 && t == 0) {
        float mean = loss_sum[0] / 32768.0f;
        out[8388608] = 0.25f * (1.0f - mean);
        out[8388609] = 1.0f - mean;
    }
}

extern "C" void kernel_launch(void* const* d_in, const int* in_sizes, int n_in,
                              void* d_out, int out_size, void* d_ws, size_t ws_size,
                              hipStream_t stream) {
    const float* x  = (const float*)d_in[0];   // [8,256,64,64]
    const float* cb = (const float*)d_in[1];   // [8192,256]
    float* out = (float*)d_out;

    char* ws = (char*)d_ws;
    float* pval     = (float*)ws;                          // 64*32768*4 = 8 MB
    int*   pidx     = (int*)(ws + 8388608);                // 8 MB
    float* norms    = (float*)(ws + 16777216);             // 128 KB
    int*   idx_best = (int*)(ws + 16777216 + 131072);      // 128 KB
    float* loss_sum = (float*)(ws + 16777216 + 262144);    // 4 B

    hipMemsetAsync(loss_sum, 0, 4, stream);
    norms_kernel<<<512, 256, 0, stream>>>(x, norms);
    gemm_argmax_kernel<<<dim3(64, 256), 256, 0, stream>>>(x, cb, pval, pidx);
    reduce_kernel<<<128, 256, 0, stream>>>(pval, pidx, norms, idx_best, loss_sum);
    writeq_kernel<<<512, 256, 0, stream>>>(cb, idx_best, loss_sum, out);
}

// Round 2
// 2330.802 us; speedup vs baseline: 1.1122x; 1.1122x over previous
//
#include <hip/hip_runtime.h>
#include <hip/hip_bf16.h>
#include <cstdint>

#define HWP    4096
#define CDIM   256
#define KCODES 8192
#define NROWS  32768
#define NKB    64          // 8192 / 128 code-blocks

typedef __bf16 bf16x8 __attribute__((ext_vector_type(8)));
typedef float  f32x4  __attribute__((ext_vector_type(4)));

// ---- async global->LDS, 16B per lane; LDS dest = uniform base + lane*16 ----
__device__ __forceinline__ void load16_to_lds(const void* g, void* s) {
    __builtin_amdgcn_global_load_lds(
        (const __attribute__((address_space(1))) void*)(uintptr_t)g,
        (__attribute__((address_space(3))) void*)(uintptr_t)s,
        16, 0, 0);
}

// ---- index-aware top-2 insert (first-index on value ties, dedup by index) ----
__device__ __forceinline__ void ins2(float v, int i,
                                     float& v1, int& i1, float& v2, int& i2) {
    if (i == i1 || i == i2) return;
    bool b1 = (v > v1) || (v == v1 && i < i1);
    bool b2 = (v > v2) || (v == v2 && i < i2);
    if (b1) { v2 = v1; i2 = i1; v1 = v; i1 = i; }
    else if (b2) { v2 = v; i2 = i; }
}

// =============== Kernel 1a: split+transpose x -> xT_hi/xT_lo [N][C] bf16 ======
__global__ __launch_bounds__(256) void split_x_kernel(const float* __restrict__ x,
                                                      __bf16* __restrict__ xh,
                                                      __bf16* __restrict__ xl) {
    __shared__ float tile[64][65];
    int pb = blockIdx.x, cbk = blockIdx.y, b = blockIdx.z;
    int t = threadIdx.x;
    int p0 = pb * 64, c0 = cbk * 64;
    int pl = t & 63, cl = t >> 6;
    const float* src = x + ((size_t)b * CDIM + c0) * HWP + p0;
    #pragma unroll 4
    for (int i = 0; i < 16; ++i) {
        int c = cl * 16 + i;
        tile[c][pl] = src[(size_t)c * HWP + pl];
    }
    __syncthreads();
    int p = t >> 2, cq = (t & 3) * 16;
    size_t n = (size_t)b * HWP + p0 + p;
    alignas(16) __bf16 hbuf[16];
    alignas(16) __bf16 lbuf[16];
    #pragma unroll
    for (int j = 0; j < 16; ++j) {
        float v = tile[cq + j][p];
        __bf16 h = (__bf16)v;
        hbuf[j] = h;
        lbuf[j] = (__bf16)(v - (float)h);
    }
    *(int4*)(xh + n * CDIM + c0 + cq)     = ((int4*)hbuf)[0];
    *(int4*)(xh + n * CDIM + c0 + cq + 8) = ((int4*)hbuf)[1];
    *(int4*)(xl + n * CDIM + c0 + cq)     = ((int4*)lbuf)[0];
    *(int4*)(xl + n * CDIM + c0 + cq + 8) = ((int4*)lbuf)[1];
}

// =============== Kernel 1b: split codebook (already [K][C]) ===================
__global__ __launch_bounds__(256) void split_cb_kernel(const float* __restrict__ cb,
                                                       __bf16* __restrict__ ch,
                                                       __bf16* __restrict__ cl) {
    int i4 = blockIdx.x * 256 + threadIdx.x;          // 2048 blocks * 256 * 4 elems
    float4 v = ((const float4*)cb)[i4];
    alignas(8) __bf16 h[4], l[4];
    float vv[4] = {v.x, v.y, v.z, v.w};
    #pragma unroll
    for (int j = 0; j < 4; ++j) {
        __bf16 hh = (__bf16)vv[j];
        h[j] = hh;
        l[j] = (__bf16)(vv[j] - (float)hh);
    }
    *(uint2*)(ch + (size_t)i4 * 4) = *(uint2*)h;
    *(uint2*)(cl + (size_t)i4 * 4) = *(uint2*)l;
}

// =============== Kernel 2: split-bf16 MFMA GEMM + per-(row,kb) top-2 ==========
// grid (mb=256, kb=64), 256 threads (4 waves). Wave w: rows w*32..+31, all 128 codes.
__global__ __launch_bounds__(256, 2) void gemm_kernel(const __bf16* __restrict__ xh,
                                                      const __bf16* __restrict__ xl,
                                                      const __bf16* __restrict__ ch,
                                                      const __bf16* __restrict__ cl,
                                                      float4* __restrict__ ptop) {
    __shared__ __bf16 sAh[128 * 64];
    __shared__ __bf16 sAl[128 * 64];
    __shared__ __bf16 sBh[128 * 64];
    __shared__ __bf16 sBl[128 * 64];

    int t = threadIdx.x;
    int mb = blockIdx.x, kb = blockIdx.y;
    int n0 = mb * 128, k0 = kb * 128;
    int w = t >> 6, lane = t & 63;
    int qq = lane >> 4, cc2 = lane & 15;

    f32x4 acc[2][8];
    f32x4 zero = {0.f, 0.f, 0.f, 0.f};
    #pragma unroll
    for (int mi = 0; mi < 2; ++mi)
        #pragma unroll
        for (int ni = 0; ni < 8; ++ni) acc[mi][ni] = zero;

    for (int cs = 0; cs < CDIM; cs += 64) {
        __syncthreads();
        // Stage 4 tiles (Ah, Al, Bh, Bl), 128 rows x 64 c each, XOR-swizzled:
        // LDS slot (r, c8) holds global (r, c8 ^ (r&7)).
        #pragma unroll
        for (int it = 0; it < 4; ++it) {
            int chunk = (w * 4 + it) * 64 + lane;
            int r  = chunk >> 3;
            int sw = (chunk & 7) ^ (r & 7);
            size_t aoff = (size_t)(n0 + r) * CDIM + cs + sw * 8;
            size_t boff = (size_t)(k0 + r) * CDIM + cs + sw * 8;
            unsigned lo = (unsigned)((w * 4 + it) * 1024);
            load16_to_lds(xh + aoff, (char*)sAh + lo);
            load16_to_lds(xl + aoff, (char*)sAl + lo);
            load16_to_lds(ch + boff, (char*)sBh + lo);
            load16_to_lds(cl + boff, (char*)sBl + lo);
        }
        __syncthreads();

        #pragma unroll
        for (int kk = 0; kk < 2; ++kk) {
            bf16x8 ah[2], al[2];
            #pragma unroll
            for (int mi = 0; mi < 2; ++mi) {
                int m  = w * 32 + mi * 16 + cc2;
                int sw = ((kk << 2) | qq) ^ (m & 7);
                ah[mi] = *(const bf16x8*)((const char*)sAh + m * 128 + sw * 16);
                al[mi] = *(const bf16x8*)((const char*)sAl + m * 128 + sw * 16);
            }
            #pragma unroll
            for (int ni = 0; ni < 8; ++ni) {
                int nn = ni * 16 + cc2;
                int sw = ((kk << 2) | qq) ^ (nn & 7);
                bf16x8 bh = *(const bf16x8*)((const char*)sBh + nn * 128 + sw * 16);
                bf16x8 bl = *(const bf16x8*)((const char*)sBl + nn * 128 + sw * 16);
                #pragma unroll
                for (int mi = 0; mi < 2; ++mi) {
                    acc[mi][ni] = __builtin_amdgcn_mfma_f32_16x16x32_bf16(ah[mi], bh, acc[mi][ni], 0, 0, 0);
                    acc[mi][ni] = __builtin_amdgcn_mfma_f32_16x16x32_bf16(ah[mi], bl, acc[mi][ni], 0, 0, 0);
                    acc[mi][ni] = __builtin_amdgcn_mfma_f32_16x16x32_bf16(al[mi], bh, acc[mi][ni], 0, 0, 0);
                }
            }
        }
    }

    // Epilogue: per-row top-2 over this kb's 128 codes.
    // C/D layout: col(code) = lane&15, row = (lane>>4)*4 + reg.
    #pragma unroll
    for (int mi = 0; mi < 2; ++mi) {
        #pragma unroll
        for (int r = 0; r < 4; ++r) {
            float v1 = -3.4e38f, v2 = -3.4e38f;
            int   i1 = 0x7fffffff, i2 = 0x7fffffff;
            #pragma unroll
            for (int ni = 0; ni < 8; ++ni)
                ins2(acc[mi][ni][r], k0 + ni * 16 + cc2, v1, i1, v2, i2);
            #pragma unroll
            for (int msk = 1; msk <= 8; msk <<= 1) {
                float ov1 = __shfl_xor(v1, msk); int oi1 = __shfl_xor(i1, msk);
                float ov2 = __shfl_xor(v2, msk); int oi2 = __shfl_xor(i2, msk);
                ins2(ov1, oi1, v1, i1, v2, i2);
                ins2(ov2, oi2, v1, i1, v2, i2);
            }
            if (cc2 == mi * 4 + r) {
                int row = n0 + w * 32 + mi * 16 + qq * 4 + r;
                float4 e;
                e.x = v1; e.y = __int_as_float(i1);
                e.z = v2; e.w = __int_as_float(i2);
                ptop[(size_t)kb * NROWS + row] = e;
            }
        }
    }
}

// =============== Kernel 3: merge 64 k-blocks -> global top-2 candidates =======
__global__ __launch_bounds__(256) void reduce_kernel(const float4* __restrict__ ptop,
                                                     int2* __restrict__ cand) {
    int n = blockIdx.x * 256 + threadIdx.x;   // 128 blocks
    float v1 = -3.4e38f, v2 = -3.4e38f;
    int   i1 = 0x7fffffff, i2 = 0x7fffffff;
    for (int kb = 0; kb < NKB; ++kb) {
        float4 e = ptop[(size_t)kb * NROWS + n];
        ins2(e.x, __float_as_int(e.y), v1, i1, v2, i2);
        ins2(e.z, __float_as_int(e.w), v1, i1, v2, i2);
    }
    cand[n] = make_int2(i1, i2);
}

// =============== Kernel 4: exact fp32 rescore of 2 candidates + q write + loss =
__global__ __launch_bounds__(256) void rescore_kernel(const float* __restrict__ x,
                                                      const float* __restrict__ cb,
                                                      const int2* __restrict__ cand,
                                                      float* __restrict__ out,
                                                      float* __restrict__ loss_sum) {
    int blk = blockIdx.x;                 // 512 blocks, 64 rows each
    int b = blk >> 6;
    int p0 = (blk & 63) << 6;
    int t = threadIdx.x, w = t >> 6, lane = t & 63;
    size_t rowbase = (size_t)b * HWP + p0;
    int2 cd = cand[rowbase + lane];
    const float* xb = x + (size_t)b * CDIM * HWP + p0 + lane;
    const float* c1 = cb + (size_t)cd.x * CDIM;
    const float* c2 = cb + (size_t)cd.y * CDIM;
    float n2 = 0.f, d1 = 0.f, d2 = 0.f;
    for (int c = w * 64; c < w * 64 + 64; ++c) {
        float xv = xb[(size_t)c * HWP];
        n2 = fmaf(xv, xv, n2);
        d1 = fmaf(xv, c1[c], d1);
        d2 = fmaf(xv, c2[c], d2);
    }
    __shared__ float s_n2[4][64], s_d1[4][64], s_d2[4][64];
    __shared__ int   s_win[64];
    __shared__ float s_loss[64];
    s_n2[w][lane] = n2; s_d1[w][lane] = d1; s_d2[w][lane] = d2;
    __syncthreads();
    if (t < 64) {
        float N2 = s_n2[0][t] + s_n2[1][t] + s_n2[2][t] + s_n2[3][t];
        float D1 = s_d1[0][t] + s_d1[1][t] + s_d1[2][t] + s_d1[3][t];
        float D2 = s_d2[0][t] + s_d2[1][t] + s_d2[2][t] + s_d2[3][t];
        int2 cdt = cand[rowbase + t];
        bool take1 = (D1 > D2) || (D1 == D2 && cdt.x < cdt.y);
        s_win[t]  = take1 ? cdt.x : cdt.y;
        s_loss[t] = (take1 ? D1 : D2) / fmaxf(sqrtf(N2), 1e-12f);
    }
    __syncthreads();
    if (w == 0) {
        float v = s_loss[lane];
        #pragma unroll
        for (int off = 32; off; off >>= 1) v += __shfl_down(v, off);
        if (lane == 0) atomicAdd(loss_sum, v);
    }
    int win = s_win[lane];
    const float* cw = cb + (size_t)win * CDIM;
    float* ob = out + (size_t)b * CDIM * HWP + p0 + lane;
    for (int c = w * 64; c < w * 64 + 64; ++c)
        ob[(size_t)c * HWP] = cw[c];
}

// =============== Kernel 5: finalize losses ====================================
__global__ void finalize_kernel(const float* __restrict__ loss_sum,
                                float* __restrict__ out) {
    if (threadIdx.x == 0) {
        float mean = loss_sum[0] / 32768.0f;
        out[8388608] = 0.25f * (1.0f - mean);
        out[8388609] = 1.0f  * (1.0f - mean);
    }
}

extern "C" void kernel_launch(void* const* d_in, const int* in_sizes, int n_in,
                              void* d_out, int out_size, void* d_ws, size_t ws_size,
                              hipStream_t stream) {
    const float* x  = (const float*)d_in[0];   // [8,256,64,64]
    const float* cb = (const float*)d_in[1];   // [8192,256]
    float* out = (float*)d_out;

    char* ws = (char*)d_ws;
    __bf16* xh   = (__bf16*)(ws);                         // 16,777,216 B
    __bf16* xl   = (__bf16*)(ws + 16777216);              // 16,777,216 B
    __bf16* ch   = (__bf16*)(ws + 33554432);              //  4,194,304 B
    __bf16* cl   = (__bf16*)(ws + 37748736);              //  4,194,304 B
    float4* ptop = (float4*)(ws + 41943040);              // 33,554,432 B
    int2*   cand = (int2*)  (ws + 75497472);              //    262,144 B
    float*  loss = (float*) (ws + 75759616);              //          4 B

    hipMemsetAsync(loss, 0, 4, stream);
    split_x_kernel <<<dim3(64, 4, 8), 256, 0, stream>>>(x, xh, xl);
    split_cb_kernel<<<2048,           256, 0, stream>>>(cb, ch, cl);
    gemm_kernel    <<<dim3(256, 64),  256, 0, stream>>>(xh, xl, ch, cl, ptop);
    reduce_kernel  <<<128,            256, 0, stream>>>(ptop, cand);
    rescore_kernel <<<512,            256, 0, stream>>>(x, cb, cand, out, loss);
    finalize_kernel<<<1,              64,  0, stream>>>(loss, out);
}